// Round 5
// baseline (319.347 us; speedup 1.0000x reference)
//
#include <hip/hip_runtime.h>
#include <math.h>

#define NN 4096
#define HID 256
#define MD 32
#define NH 8
#define SCALE 0.17677669529663687f  // 1/sqrt(32)

typedef float f32x4 __attribute__((ext_vector_type(4)));
typedef short bf16x8 __attribute__((ext_vector_type(8)));
typedef _Float16 f16x4 __attribute__((ext_vector_type(4)));
typedef _Float16 f16x2 __attribute__((ext_vector_type(2)));

__device__ inline unsigned int bfr(float x) {             // f32 -> bf16 bits (RNE)
    unsigned int u = __float_as_uint(x);
    return (u + 0x7fffu + ((u >> 16) & 1u)) >> 16;
}
__device__ inline unsigned int pkbf(float a, float b) {   // pack 2 bf16 into u32
    return bfr(a) | (bfr(b) << 16);
}
__device__ inline unsigned int pkhf(float a, float b) {   // pack 2 f16 (RNE) into u32
    union { f16x2 h; unsigned int u; } z;
    z.h = (f16x2){(_Float16)a, (_Float16)b};
    return z.u;
}

// ---------------- projections: Q=NF@Wq+bq, K=NF@Wk+bk, V=MSG@Wv+bv --------
__global__ __launch_bounds__(256) void proj_kernel(
    const float* __restrict__ nf, const float* __restrict__ msg,
    const float* __restrict__ Wq, const float* __restrict__ bq,
    const float* __restrict__ Wk, const float* __restrict__ bk,
    const float* __restrict__ Wv, const float* __restrict__ bv,
    float* __restrict__ Qo, float* __restrict__ Ko, float* __restrict__ Vo)
{
    __shared__ __align__(16) float in_lds[32 * 256];
    const int b = blockIdx.x;
    const int which = b >> 7;     // 0:Q 1:K 2:V (128 blocks each)
    const int nb = b & 127;
    const float* in; const float* W; const float* bias; float* out; int KD;
    if (which == 0)      { in = nf;  W = Wq; bias = bq; out = Qo; KD = 256; }
    else if (which == 1) { in = nf;  W = Wk; bias = bk; out = Ko; KD = 256; }
    else                 { in = msg; W = Wv; bias = bv; out = Vo; KD = 32;  }
    const int t = threadIdx.x;
    const int n4 = (32 * KD) >> 2;
    const float4* src = (const float4*)(in + (size_t)nb * 32 * KD);
    for (int i = t; i < n4; i += 256) ((float4*)in_lds)[i] = src[i];
    __syncthreads();

    float acc[32];
    #pragma unroll
    for (int r = 0; r < 32; ++r) acc[r] = 0.f;
    for (int k = 0; k < KD; ++k) {
        float w = W[k * 256 + t];
        #pragma unroll
        for (int r = 0; r < 32; ++r) acc[r] += in_lds[r * KD + k] * w;
    }
    const float bb = bias[t];
    #pragma unroll
    for (int r = 0; r < 32; ++r) out[(size_t)(nb * 32 + r) * 256 + t] = acc[r] + bb;
}

// ------------- pack adjacency into bitmask: abit[n][64] u64 ---------------
__global__ __launch_bounds__(256) void abit_kernel(
    const int* __restrict__ adj, unsigned long long* __restrict__ abit)
{
    const int n = blockIdx.x * 4 + (threadIdx.x >> 6);
    const int l = threadIdx.x & 63;
    for (int j = 0; j < 64; ++j) {
        int v = adj[(size_t)n * NN + j * 64 + l];
        unsigned long long m = __ballot(v != 0);
        if (l == 0) abit[(size_t)n * 64 + j] = m;
    }
}

// -------- pack Q,K f32[n][256] -> bf16 head-major [h][n][32] --------------
__global__ __launch_bounds__(256) void pack_qk(
    const float* __restrict__ Qf, const float* __restrict__ Kf,
    unsigned short* __restrict__ Qb, unsigned short* __restrict__ Kb)
{
    int i = blockIdx.x * 256 + threadIdx.x;     // 0..262143
    int isK = i >= 131072;
    int j = i & 131071;                          // (n, c8)
    int n = j >> 5, c8 = j & 31;
    const float* src = (isK ? Kf : Qf) + (size_t)n * 256 + c8 * 8;
    float4 a = ((const float4*)src)[0];
    float4 b = ((const float4*)src)[1];
    float sc = isK ? 1.0f : SCALE;
    a.x *= sc; a.y *= sc; a.z *= sc; a.w *= sc;
    b.x *= sc; b.y *= sc; b.z *= sc; b.w *= sc;
    int h = c8 >> 2, d = (c8 & 3) * 8;
    unsigned short* dst = (isK ? Kb : Qb) + (((size_t)h * NN + n) << 5) + d;
    uint4 o;
    o.x = pkbf(a.x, a.y); o.y = pkbf(a.z, a.w);
    o.z = pkbf(b.x, b.y); o.w = pkbf(b.z, b.w);
    *(uint4*)dst = o;
}

// -------- pack V f32[m][256] -> f16 transposed Vt[h][d][m] ----------------
__global__ __launch_bounds__(256) void pack_vt(
    const float* __restrict__ Vf, unsigned short* __restrict__ Vt)
{
    __shared__ __align__(16) float lds[128 * 33];
    const int h = blockIdx.x >> 5, mt = blockIdx.x & 31;  // m-tile of 128
    const int t = threadIdx.x;
    for (int k = 0; k < 4; ++k) {
        int flat = k * 256 + t;            // 0..1023 float4 slots
        int row = flat >> 3, c4 = flat & 7;
        float4 v = *(const float4*)(Vf + (size_t)(mt * 128 + row) * 256 + h * 32 + c4 * 4);
        lds[row * 33 + c4 * 4 + 0] = v.x;
        lds[row * 33 + c4 * 4 + 1] = v.y;
        lds[row * 33 + c4 * 4 + 2] = v.z;
        lds[row * 33 + c4 * 4 + 3] = v.w;
    }
    __syncthreads();
    const int d = t >> 3, mq = t & 7;      // each writes 16 m for one d
    #pragma unroll
    for (int k = 0; k < 2; ++k) {
        int m0 = mq * 16 + k * 8;
        uint4 o;
        o.x = pkhf(lds[(m0 + 0) * 33 + d], lds[(m0 + 1) * 33 + d]);
        o.y = pkhf(lds[(m0 + 2) * 33 + d], lds[(m0 + 3) * 33 + d]);
        o.z = pkhf(lds[(m0 + 4) * 33 + d], lds[(m0 + 5) * 33 + d]);
        o.w = pkhf(lds[(m0 + 6) * 33 + d], lds[(m0 + 7) * 33 + d]);
        *(uint4*)(Vt + ((size_t)(h * 32 + d)) * NN + mt * 128 + m0) = o;
    }
}

// ---------------- sweep 1: L partials via MFMA QK^T -----------------------
// block: (ntile, msgroup); wave w -> msplit = msgroup*4+w, m range 256
__global__ __launch_bounds__(256, 4) void sweep1_kernel(
    const unsigned short* __restrict__ Qb, const unsigned short* __restrict__ Kb,
    const unsigned int* __restrict__ abit, float* __restrict__ Lpart)
{
    const int ntile = blockIdx.x, msg = blockIdx.y;
    const int t = threadIdx.x;
    const int w = t >> 6, l = t & 63;
    const int g = l >> 4, q = l & 15;
    const int ms = msg * 4 + w;
    const int n0 = ntile * 16;
    const int mbase = ms * 256;

    bf16x8 qf[8];
    #pragma unroll
    for (int h = 0; h < 8; ++h)
        qf[h] = *(const bf16x8*)(Qb + (((size_t)h * NN + n0 + q) << 5) + g * 8);

    float lacc[8];
    #pragma unroll
    for (int h = 0; h < 8; ++h) lacc[h] = 0.f;

    for (int ch = 0; ch < 8; ++ch) {
        const int mb = mbase + ch * 32;
        const unsigned int wbits = abit[(size_t)(n0 + q) * 128 + (mb >> 5)];
        #pragma unroll
        for (int h = 0; h < 8; ++h) {
            bf16x8 ka0 = *(const bf16x8*)(Kb + (((size_t)h * NN + mb + q) << 5) + g * 8);
            bf16x8 ka1 = *(const bf16x8*)(Kb + (((size_t)h * NN + mb + 16 + q) << 5) + g * 8);
            f32x4 z = {0.f, 0.f, 0.f, 0.f};
            f32x4 s0 = __builtin_amdgcn_mfma_f32_16x16x32_bf16(ka0, qf[h], z, 0, 0, 0);
            f32x4 s1 = __builtin_amdgcn_mfma_f32_16x16x32_bf16(ka1, qf[h], z, 0, 0, 0);
            #pragma unroll
            for (int r = 0; r < 4; ++r) {
                float e0 = __expf(s0[r]);
                float e1 = __expf(s1[r]);
                lacc[h] += ((wbits >> (4 * g + r)) & 1u) ? e0 : 0.f;
                lacc[h] += ((wbits >> (16 + 4 * g + r)) & 1u) ? e1 : 0.f;
            }
        }
    }
    #pragma unroll
    for (int h = 0; h < 8; ++h) {
        float v = lacc[h];
        v += __shfl_xor(v, 16);
        v += __shfl_xor(v, 32);
        if (g == 0) Lpart[(size_t)ms * 32768 + h * NN + n0 + q] = v;
    }
}

// ---------------- Linv[h][n] = 1 / sum_ms Lpart ---------------------------
__global__ __launch_bounds__(256) void linv_kernel(
    const float* __restrict__ Lpart, float* __restrict__ Linv)
{
    int i = blockIdx.x * 256 + threadIdx.x;   // 0..32767
    float s = 0.f;
    #pragma unroll
    for (int ms = 0; ms < 16; ++ms) s += Lpart[(size_t)ms * 32768 + i];
    Linv[i] = 1.0f / s;
}

// ---------------- sweep 2: amean + PV partials via MFMA -------------------
// PV uses K=16 f16 MFMA: B-operand wants k=4g+j, exactly the QK C-layout
// (m=4g+r) -> P stays lane-local, NO cross-lane exchange, NO LDS in loop.
__global__ __launch_bounds__(256, 2) void sweep2_kernel(
    const unsigned short* __restrict__ Qb, const unsigned short* __restrict__ Kb,
    const _Float16* __restrict__ Vt, const unsigned int* __restrict__ abit,
    const float* __restrict__ Linv, float* __restrict__ Opart,
    float* __restrict__ amean)
{
    __shared__ __align__(16) float Ow[2 * 16 * 260];
    const int ntile = blockIdx.x, msg = blockIdx.y;
    const int t = threadIdx.x;
    const int w = t >> 6, l = t & 63;
    const int g = l >> 4, q = l & 15;
    const int ms = msg * 4 + w;
    const int n0 = ntile * 16;
    const int mbase = ms * 256;

    bf16x8 qf[8];
    float rL[8];
    #pragma unroll
    for (int h = 0; h < 8; ++h) {
        qf[h] = *(const bf16x8*)(Qb + (((size_t)h * NN + n0 + q) << 5) + g * 8);
        rL[h] = Linv[h * NN + n0 + q];
    }
    f32x4 o[8][2];
    #pragma unroll
    for (int h = 0; h < 8; ++h) {
        o[h][0] = (f32x4){0.f, 0.f, 0.f, 0.f};
        o[h][1] = (f32x4){0.f, 0.f, 0.f, 0.f};
    }

    for (int ch = 0; ch < 8; ++ch) {
        const int mb = mbase + ch * 32;
        const unsigned int wbits = abit[(size_t)(n0 + q) * 128 + (mb >> 5)];
        float am[8];
        #pragma unroll
        for (int r = 0; r < 8; ++r) am[r] = 0.f;

        #pragma unroll
        for (int h = 0; h < 8; ++h) {
            bf16x8 ka0 = *(const bf16x8*)(Kb + (((size_t)h * NN + mb + q) << 5) + g * 8);
            bf16x8 ka1 = *(const bf16x8*)(Kb + (((size_t)h * NN + mb + 16 + q) << 5) + g * 8);
            f32x4 z = {0.f, 0.f, 0.f, 0.f};
            f32x4 s0 = __builtin_amdgcn_mfma_f32_16x16x32_bf16(ka0, qf[h], z, 0, 0, 0);
            f32x4 s1 = __builtin_amdgcn_mfma_f32_16x16x32_bf16(ka1, qf[h], z, 0, 0, 0);
            float pn[8];
            #pragma unroll
            for (int r = 0; r < 4; ++r) {
                float e0 = __expf(s0[r]) * rL[h];
                float e1 = __expf(s1[r]) * rL[h];
                pn[r]     = ((wbits >> (4 * g + r)) & 1u) ? e0 : 0.f;
                pn[4 + r] = ((wbits >> (16 + 4 * g + r)) & 1u) ? e1 : 0.f;
                am[r] += pn[r];
                am[4 + r] += pn[4 + r];
            }
            // P fragments, lane-local: m16=mb -> pn[0..3], m16=mb+16 -> pn[4..7]
            union { unsigned int u[2]; f16x4 v; } pA, pB;
            pA.u[0] = pkhf(pn[0], pn[1]); pA.u[1] = pkhf(pn[2], pn[3]);
            pB.u[0] = pkhf(pn[4], pn[5]); pB.u[1] = pkhf(pn[6], pn[7]);
            // V fragments: A row = d (=q / 16+q), k = 4g+j -> m16 + 4g + j
            const _Float16* vb = Vt + ((size_t)(h * 32 + q)) * NN + mb + 4 * g;
            f16x4 va00 = *(const f16x4*)(vb);
            f16x4 va10 = *(const f16x4*)(vb + 16);
            const _Float16* vc = vb + (size_t)16 * NN;
            f16x4 va01 = *(const f16x4*)(vc);
            f16x4 va11 = *(const f16x4*)(vc + 16);
            o[h][0] = __builtin_amdgcn_mfma_f32_16x16x16f16(va00, pA.v, o[h][0], 0, 0, 0);
            o[h][1] = __builtin_amdgcn_mfma_f32_16x16x16f16(va01, pA.v, o[h][1], 0, 0, 0);
            o[h][0] = __builtin_amdgcn_mfma_f32_16x16x16f16(va10, pB.v, o[h][0], 0, 0, 0);
            o[h][1] = __builtin_amdgcn_mfma_f32_16x16x16f16(va11, pB.v, o[h][1], 0, 0, 0);
        }
        // amean write: lane owns row n0+q, m = mb + 4g(+16)
        float4 a0, a1;
        a0.x = am[0] * 0.125f; a0.y = am[1] * 0.125f;
        a0.z = am[2] * 0.125f; a0.w = am[3] * 0.125f;
        a1.x = am[4] * 0.125f; a1.y = am[5] * 0.125f;
        a1.z = am[6] * 0.125f; a1.w = am[7] * 0.125f;
        *(float4*)(amean + (size_t)(n0 + q) * NN + mb + 4 * g) = a0;
        *(float4*)(amean + (size_t)(n0 + q) * NN + mb + 16 + 4 * g) = a1;
    }

    // -------- block reduce O across the 4 waves (2-stage, 33 KB LDS) ------
    if (w < 2) {
        #pragma unroll
        for (int h = 0; h < 8; ++h) {
            #pragma unroll
            for (int dt = 0; dt < 2; ++dt)
                *(f32x4*)&Ow[w * 4160 + q * 260 + h * 32 + dt * 16 + 4 * g] = o[h][dt];
        }
    }
    __syncthreads();
    if (w >= 2) {
        #pragma unroll
        for (int h = 0; h < 8; ++h) {
            #pragma unroll
            for (int dt = 0; dt < 2; ++dt) {
                f32x4* p = (f32x4*)&Ow[(w - 2) * 4160 + q * 260 + h * 32 + dt * 16 + 4 * g];
                *p = *p + o[h][dt];
            }
        }
    }
    __syncthreads();
    for (int i = t; i < 4096; i += 256) {
        int n = i >> 8, c = i & 255;
        float v = Ow[n * 260 + c] + Ow[4160 + n * 260 + c];
        Opart[((size_t)msg * NN + n0 + n) * 256 + c] = v;
    }
}

// -------- finalize: routed = (sum_msg Opart) @ Wo + bo --------------------
__global__ __launch_bounds__(256) void final_kernel(
    const float* __restrict__ accpart, const float* __restrict__ Wo,
    const float* __restrict__ bo, float* __restrict__ routed)
{
    __shared__ float sacc[32 * 257];
    const int nb = blockIdx.x, t = threadIdx.x;
    for (int i = t; i < 8192; i += 256) {
        int r = i >> 8, c = i & 255;
        int n = nb * 32 + r;
        float s = 0.f;
        #pragma unroll
        for (int ms = 0; ms < 4; ++ms)
            s += accpart[((size_t)ms * NN + n) * 256 + c];
        sacc[r * 257 + c] = s;
    }
    __syncthreads();
    const int j = t & 31, r0 = t >> 5;
    #pragma unroll
    for (int rr = 0; rr < 4; ++rr) {
        int r = r0 * 4 + rr;
        float s = bo[j];
        for (int i = 0; i < 256; ++i) s += sacc[r * 257 + i] * Wo[i * 32 + j];
        routed[(size_t)(nb * 32 + r) * 32 + j] = s;
    }
}

extern "C" void kernel_launch(void* const* d_in, const int* in_sizes, int n_in,
                              void* d_out, int out_size, void* d_ws, size_t ws_size,
                              hipStream_t stream) {
    const float* nf  = (const float*)d_in[0];
    const float* msg = (const float*)d_in[1];
    const int*   adj = (const int*)d_in[2];
    const float* Wq  = (const float*)d_in[3];
    const float* bq  = (const float*)d_in[4];
    const float* Wk  = (const float*)d_in[5];
    const float* bk  = (const float*)d_in[6];
    const float* Wv  = (const float*)d_in[7];
    const float* bv  = (const float*)d_in[8];
    const float* Wo  = (const float*)d_in[9];
    const float* bo  = (const float*)d_in[10];

    float* routed = (float*)d_out;
    float* amean  = (float*)d_out + (size_t)NN * MD;

    float* ws = (float*)d_ws;
    float* Qf = ws;                       // 1048576
    float* Kf = ws + 1048576;             // 1048576
    float* Vf = ws + 2097152;             // 1048576
    float* Opart = ws;                    // 4*4096*256 (aliases Qf/Kf/Vf, dead then)
    unsigned short* Qb = (unsigned short*)(ws + 4194304);   // 2MB
    unsigned short* Kb = (unsigned short*)(ws + 4718592);   // 2MB
    unsigned short* Vt = (unsigned short*)(ws + 5242880);   // 2MB (f16)
    unsigned int*   ab32 = (unsigned int*)(ws + 5767168);   // 2MB
    unsigned long long* ab64 = (unsigned long long*)(ws + 5767168);
    float* Lpart = ws + 6291456;          // 16*8*4096
    float* Linv  = ws + 6815744;          // 32768

    proj_kernel<<<384, 256, 0, stream>>>(nf, msg, Wq, bq, Wk, bk, Wv, bv, Qf, Kf, Vf);
    abit_kernel<<<1024, 256, 0, stream>>>(adj, ab64);
    pack_qk<<<1024, 256, 0, stream>>>(Qf, Kf, Qb, Kb);
    pack_vt<<<256, 256, 0, stream>>>(Vf, Vt);
    sweep1_kernel<<<dim3(256, 4), 256, 0, stream>>>(Qb, Kb, ab32, Lpart);
    linv_kernel<<<128, 256, 0, stream>>>(Lpart, Linv);
    sweep2_kernel<<<dim3(256, 4), 256, 0, stream>>>(Qb, Kb, (const _Float16*)Vt, ab32, Linv, Opart, amean);
    final_kernel<<<128, 256, 0, stream>>>(Opart, Wo, bo, routed);
}

// Round 6
// 255.085 us; speedup vs baseline: 1.2519x; 1.2519x over previous
//
#include <hip/hip_runtime.h>
#include <math.h>

#define NN 4096
#define HID 256
#define MD 32
#define NH 8
#define SCALE 0.17677669529663687f  // 1/sqrt(32)

typedef float f32x4 __attribute__((ext_vector_type(4)));
typedef short bf16x8 __attribute__((ext_vector_type(8)));
typedef _Float16 f16x4 __attribute__((ext_vector_type(4)));
typedef _Float16 f16x2 __attribute__((ext_vector_type(2)));

__device__ inline unsigned int bfr(float x) {             // f32 -> bf16 bits (RNE)
    unsigned int u = __float_as_uint(x);
    return (u + 0x7fffu + ((u >> 16) & 1u)) >> 16;
}
__device__ inline unsigned int pkbf(float a, float b) {
    return bfr(a) | (bfr(b) << 16);
}
__device__ inline unsigned int pkhf(float a, float b) {   // 2 x f16 (RNE)
    union { f16x2 h; unsigned int u; } z;
    z.h = (f16x2){(_Float16)a, (_Float16)b};
    return z.u;
}

// ---------------- projections ---------------------------------------------
__global__ __launch_bounds__(256) void proj_kernel(
    const float* __restrict__ nf, const float* __restrict__ msg,
    const float* __restrict__ Wq, const float* __restrict__ bq,
    const float* __restrict__ Wk, const float* __restrict__ bk,
    const float* __restrict__ Wv, const float* __restrict__ bv,
    float* __restrict__ Qo, float* __restrict__ Ko, float* __restrict__ Vo)
{
    __shared__ __align__(16) float in_lds[32 * 256];
    const int b = blockIdx.x;
    const int which = b >> 7;
    const int nb = b & 127;
    const float* in; const float* W; const float* bias; float* out; int KD;
    if (which == 0)      { in = nf;  W = Wq; bias = bq; out = Qo; KD = 256; }
    else if (which == 1) { in = nf;  W = Wk; bias = bk; out = Ko; KD = 256; }
    else                 { in = msg; W = Wv; bias = bv; out = Vo; KD = 32;  }
    const int t = threadIdx.x;
    const int n4 = (32 * KD) >> 2;
    const float4* src = (const float4*)(in + (size_t)nb * 32 * KD);
    for (int i = t; i < n4; i += 256) ((float4*)in_lds)[i] = src[i];
    __syncthreads();
    float acc[32];
    #pragma unroll
    for (int r = 0; r < 32; ++r) acc[r] = 0.f;
    for (int k = 0; k < KD; ++k) {
        float w = W[k * 256 + t];
        #pragma unroll
        for (int r = 0; r < 32; ++r) acc[r] += in_lds[r * KD + k] * w;
    }
    const float bb = bias[t];
    #pragma unroll
    for (int r = 0; r < 32; ++r) out[(size_t)(nb * 32 + r) * 256 + t] = acc[r] + bb;
}

// ------------- adjacency bitmask ------------------------------------------
__global__ __launch_bounds__(256) void abit_kernel(
    const int* __restrict__ adj, unsigned long long* __restrict__ abit)
{
    const int n = blockIdx.x * 4 + (threadIdx.x >> 6);
    const int l = threadIdx.x & 63;
    for (int j = 0; j < 64; ++j) {
        int v = adj[(size_t)n * NN + j * 64 + l];
        unsigned long long m = __ballot(v != 0);
        if (l == 0) abit[(size_t)n * 64 + j] = m;
    }
}

// -------- Q,K f32 -> bf16 head-major [h][n][32] ---------------------------
__global__ __launch_bounds__(256) void pack_qk(
    const float* __restrict__ Qf, const float* __restrict__ Kf,
    unsigned short* __restrict__ Qb, unsigned short* __restrict__ Kb)
{
    int i = blockIdx.x * 256 + threadIdx.x;
    int isK = i >= 131072;
    int j = i & 131071;
    int n = j >> 5, c8 = j & 31;
    const float* src = (isK ? Kf : Qf) + (size_t)n * 256 + c8 * 8;
    float4 a = ((const float4*)src)[0];
    float4 b = ((const float4*)src)[1];
    float sc = isK ? 1.0f : SCALE;
    a.x *= sc; a.y *= sc; a.z *= sc; a.w *= sc;
    b.x *= sc; b.y *= sc; b.z *= sc; b.w *= sc;
    int h = c8 >> 2, d = (c8 & 3) * 8;
    unsigned short* dst = (isK ? Kb : Qb) + (((size_t)h * NN + n) << 5) + d;
    uint4 o;
    o.x = pkbf(a.x, a.y); o.y = pkbf(a.z, a.w);
    o.z = pkbf(b.x, b.y); o.w = pkbf(b.z, b.w);
    *(uint4*)dst = o;
}

// -------- V f32 -> transposed Vt[h][d][m] (f16 or bf16) -------------------
__global__ __launch_bounds__(256) void pack_vt(
    const float* __restrict__ Vf, unsigned short* __restrict__ Vt, int usef16)
{
    __shared__ __align__(16) float lds[128 * 33];
    const int h = blockIdx.x >> 5, mt = blockIdx.x & 31;
    const int t = threadIdx.x;
    for (int k = 0; k < 4; ++k) {
        int flat = k * 256 + t;
        int row = flat >> 3, c4 = flat & 7;
        float4 v = *(const float4*)(Vf + (size_t)(mt * 128 + row) * 256 + h * 32 + c4 * 4);
        lds[row * 33 + c4 * 4 + 0] = v.x;
        lds[row * 33 + c4 * 4 + 1] = v.y;
        lds[row * 33 + c4 * 4 + 2] = v.z;
        lds[row * 33 + c4 * 4 + 3] = v.w;
    }
    __syncthreads();
    const int d = t >> 3, mq = t & 7;
    #pragma unroll
    for (int k = 0; k < 2; ++k) {
        int m0 = mq * 16 + k * 8;
        uint4 o;
        if (usef16) {
            o.x = pkhf(lds[(m0 + 0) * 33 + d], lds[(m0 + 1) * 33 + d]);
            o.y = pkhf(lds[(m0 + 2) * 33 + d], lds[(m0 + 3) * 33 + d]);
            o.z = pkhf(lds[(m0 + 4) * 33 + d], lds[(m0 + 5) * 33 + d]);
            o.w = pkhf(lds[(m0 + 6) * 33 + d], lds[(m0 + 7) * 33 + d]);
        } else {
            o.x = pkbf(lds[(m0 + 0) * 33 + d], lds[(m0 + 1) * 33 + d]);
            o.y = pkbf(lds[(m0 + 2) * 33 + d], lds[(m0 + 3) * 33 + d]);
            o.z = pkbf(lds[(m0 + 4) * 33 + d], lds[(m0 + 5) * 33 + d]);
            o.w = pkbf(lds[(m0 + 6) * 33 + d], lds[(m0 + 7) * 33 + d]);
        }
        *(uint4*)(Vt + ((size_t)(h * 32 + d)) * NN + mt * 128 + m0) = o;
    }
}

// ======================= NEW STAGED SWEEPS (path A) =======================
// block: 4 waves split by n (wave w -> 16 rows); all waves share m-chunks.
// K/V staged per 32-m chunk via global_load_lds, double-buffered, XOR
// granule swizzle (gran ^ ((row>>1)&3)) applied on the GLOBAL source.

__global__ __launch_bounds__(256, 4) void sweep1s_kernel(
    const unsigned short* __restrict__ Qb, const unsigned short* __restrict__ Kb,
    const unsigned int* __restrict__ abit, float* __restrict__ Lpart)
{
    __shared__ __align__(16) char smem[32768];   // 2 x 16KB (8 K-tiles x 2KB)
    const int nquad = blockIdx.x, msg = blockIdx.y;
    const int t = threadIdx.x;
    const int w = t >> 6, l = t & 63;
    const int g = l >> 4, q = l & 15;
    const int n0 = nquad * 64 + w * 16;
    const int m0 = msg * 512;
    const int fq = (q >> 1) & 3;

    const char* gsrc[4];
    #pragma unroll
    for (int i = 0; i < 4; ++i) {
        int s = i * 256 + t;
        int tile = s >> 7;
        int r = (s >> 2) & 31;
        int gr = (s & 3) ^ ((r >> 1) & 3);
        gsrc[i] = (const char*)Kb + (((size_t)tile * NN + m0 + r) * 64 + gr * 16);
    }
    const unsigned int* abrow = abit + (size_t)(n0 + q) * 128 + msg * 16;

    bf16x8 qf[8];
    #pragma unroll
    for (int h = 0; h < 8; ++h)
        qf[h] = *(const bf16x8*)(Qb + (((size_t)h * NN + n0 + q) << 5) + g * 8);
    float lacc[8];
    #pragma unroll
    for (int h = 0; h < 8; ++h) lacc[h] = 0.f;

    // prologue: stage chunk 0
    #pragma unroll
    for (int i = 0; i < 4; ++i)
        __builtin_amdgcn_global_load_lds((const unsigned int*)gsrc[i],
            (unsigned int*)(smem + i * 4096 + w * 1024), 16, 0, 0);
    unsigned int wb = abrow[0];
    unsigned int wbn = 0;
    __syncthreads();

    for (int c = 0; c < 16; ++c) {
        const char* cur = smem + (c & 1) * 16384;
        if (c < 15) {
            wbn = abrow[c + 1];
            char* nxt = smem + ((c & 1) ^ 1) * 16384;
            #pragma unroll
            for (int i = 0; i < 4; ++i)
                __builtin_amdgcn_global_load_lds(
                    (const unsigned int*)(gsrc[i] + (size_t)(c + 1) * 2048),
                    (unsigned int*)(nxt + i * 4096 + w * 1024), 16, 0, 0);
        }
        #pragma unroll
        for (int h = 0; h < 8; ++h) {
            const int ko = h * 2048 + q * 64 + ((g ^ fq) << 4);
            bf16x8 ka0 = *(const bf16x8*)(cur + ko);
            bf16x8 ka1 = *(const bf16x8*)(cur + ko + 1024);
            f32x4 z = {0.f, 0.f, 0.f, 0.f};
            f32x4 s0 = __builtin_amdgcn_mfma_f32_16x16x32_bf16(ka0, qf[h], z, 0, 0, 0);
            f32x4 s1 = __builtin_amdgcn_mfma_f32_16x16x32_bf16(ka1, qf[h], z, 0, 0, 0);
            #pragma unroll
            for (int r = 0; r < 4; ++r) {
                float e0 = __expf(s0[r]);
                float e1 = __expf(s1[r]);
                lacc[h] += ((wb >> (4 * g + r)) & 1u) ? e0 : 0.f;
                lacc[h] += ((wb >> (16 + 4 * g + r)) & 1u) ? e1 : 0.f;
            }
        }
        __syncthreads();   // drains my gll (vmcnt) + staging visible
        wb = wbn;
    }
    #pragma unroll
    for (int h = 0; h < 8; ++h) {
        float v = lacc[h];
        v += __shfl_xor(v, 16);
        v += __shfl_xor(v, 32);
        if (g == 0) Lpart[(size_t)msg * 32768 + h * NN + n0 + q] = v;
    }
}

__global__ __launch_bounds__(256, 2) void sweep2s_kernel(
    const unsigned short* __restrict__ Qb, const unsigned short* __restrict__ Kb,
    const unsigned short* __restrict__ Vt, const unsigned int* __restrict__ abit,
    const float* __restrict__ Linv, float* __restrict__ Opart,
    float* __restrict__ amean)
{
    __shared__ __align__(16) char smem[65536];  // 2 x 32KB (8 K + 8 V tiles)
    const int nquad = blockIdx.x, msg = blockIdx.y;
    const int t = threadIdx.x;
    const int w = t >> 6, l = t & 63;
    const int g = l >> 4, q = l & 15;
    const int n0 = nquad * 64 + w * 16;
    const int m0 = msg * 512;
    const int fq = (q >> 1) & 3;

    const char* gsrc[8];
    unsigned int gstep[8];
    #pragma unroll
    for (int i = 0; i < 8; ++i) {
        int s = i * 256 + t;
        int tile = s >> 7;                       // 0..7 K, 8..15 V
        int r = (s >> 2) & 31;
        int gr = (s & 3) ^ ((r >> 1) & 3);
        if (tile < 8) {
            gsrc[i] = (const char*)Kb + (((size_t)tile * NN + m0 + r) * 64 + gr * 16);
            gstep[i] = 2048;
        } else {
            gsrc[i] = (const char*)Vt + ((((size_t)(tile - 8) * 32 + r) * NN + m0) * 2 + gr * 16);
            gstep[i] = 64;
        }
    }
    const unsigned int* abrow = abit + (size_t)(n0 + q) * 128 + msg * 16;

    bf16x8 qf[8];
    float rL[8];
    #pragma unroll
    for (int h = 0; h < 8; ++h) {
        qf[h] = *(const bf16x8*)(Qb + (((size_t)h * NN + n0 + q) << 5) + g * 8);
        rL[h] = Linv[h * NN + n0 + q];
    }
    f32x4 o[8][2];
    #pragma unroll
    for (int h = 0; h < 8; ++h) {
        o[h][0] = (f32x4){0.f, 0.f, 0.f, 0.f};
        o[h][1] = (f32x4){0.f, 0.f, 0.f, 0.f};
    }

    #pragma unroll
    for (int i = 0; i < 8; ++i)
        __builtin_amdgcn_global_load_lds((const unsigned int*)gsrc[i],
            (unsigned int*)(smem + i * 4096 + w * 1024), 16, 0, 0);
    unsigned int wb = abrow[0];
    unsigned int wbn = 0;
    __syncthreads();

    for (int c = 0; c < 16; ++c) {
        const char* cur = smem + (c & 1) * 32768;
        if (c < 15) {
            wbn = abrow[c + 1];
            char* nxt = smem + ((c & 1) ^ 1) * 32768;
            #pragma unroll
            for (int i = 0; i < 8; ++i)
                __builtin_amdgcn_global_load_lds(
                    (const unsigned int*)(gsrc[i] + (size_t)(c + 1) * gstep[i]),
                    (unsigned int*)(nxt + i * 4096 + w * 1024), 16, 0, 0);
        }
        const int mb = m0 + c * 32;
        float am[8];
        #pragma unroll
        for (int r = 0; r < 8; ++r) am[r] = 0.f;

        #pragma unroll
        for (int h = 0; h < 8; ++h) {
            const int ko = h * 2048 + q * 64 + ((g ^ fq) << 4);
            bf16x8 ka0 = *(const bf16x8*)(cur + ko);
            bf16x8 ka1 = *(const bf16x8*)(cur + ko + 1024);
            const int vbase = (8 + h) * 2048 + q * 64 + (g & 1) * 8;
            const int vo0 = vbase + (((g >> 1) ^ fq) << 4);
            const int vo1 = vbase + (((2 + (g >> 1)) ^ fq) << 4);
            f16x4 va00 = *(const f16x4*)(cur + vo0);
            f16x4 va01 = *(const f16x4*)(cur + vo0 + 1024);
            f16x4 va10 = *(const f16x4*)(cur + vo1);
            f16x4 va11 = *(const f16x4*)(cur + vo1 + 1024);
            f32x4 z = {0.f, 0.f, 0.f, 0.f};
            f32x4 s0 = __builtin_amdgcn_mfma_f32_16x16x32_bf16(ka0, qf[h], z, 0, 0, 0);
            f32x4 s1 = __builtin_amdgcn_mfma_f32_16x16x32_bf16(ka1, qf[h], z, 0, 0, 0);
            float pn[8];
            #pragma unroll
            for (int r = 0; r < 4; ++r) {
                float e0 = __expf(s0[r]) * rL[h];
                float e1 = __expf(s1[r]) * rL[h];
                pn[r]     = ((wb >> (4 * g + r)) & 1u) ? e0 : 0.f;
                pn[4 + r] = ((wb >> (16 + 4 * g + r)) & 1u) ? e1 : 0.f;
                am[r] += pn[r];
                am[4 + r] += pn[4 + r];
            }
            union { unsigned int u[2]; f16x4 v; } pA, pB;
            pA.u[0] = pkhf(pn[0], pn[1]); pA.u[1] = pkhf(pn[2], pn[3]);
            pB.u[0] = pkhf(pn[4], pn[5]); pB.u[1] = pkhf(pn[6], pn[7]);
            o[h][0] = __builtin_amdgcn_mfma_f32_16x16x16f16(va00, pA.v, o[h][0], 0, 0, 0);
            o[h][1] = __builtin_amdgcn_mfma_f32_16x16x16f16(va01, pA.v, o[h][1], 0, 0, 0);
            o[h][0] = __builtin_amdgcn_mfma_f32_16x16x16f16(va10, pB.v, o[h][0], 0, 0, 0);
            o[h][1] = __builtin_amdgcn_mfma_f32_16x16x16f16(va11, pB.v, o[h][1], 0, 0, 0);
        }
        float4 a0, a1;
        a0.x = am[0] * 0.125f; a0.y = am[1] * 0.125f;
        a0.z = am[2] * 0.125f; a0.w = am[3] * 0.125f;
        a1.x = am[4] * 0.125f; a1.y = am[5] * 0.125f;
        a1.z = am[6] * 0.125f; a1.w = am[7] * 0.125f;
        *(float4*)(amean + (size_t)(n0 + q) * NN + mb + 4 * g) = a0;
        *(float4*)(amean + (size_t)(n0 + q) * NN + mb + 16 + 4 * g) = a1;
        __syncthreads();
        wb = wbn;
    }

    // epilogue: each wave owns its 16 n-rows x all 256 cols; direct store
    float* op = Opart + ((size_t)msg * NN + n0 + q) * 256;
    #pragma unroll
    for (int h = 0; h < 8; ++h) {
        *(f32x4*)(op + h * 32 + 4 * g) = o[h][0];
        *(f32x4*)(op + h * 32 + 16 + 4 * g) = o[h][1];
    }
}

// ======================= OLD SWEEPS (path B fallback) =====================
__global__ __launch_bounds__(256, 4) void sweep1_old(
    const unsigned short* __restrict__ Qb, const unsigned short* __restrict__ Kb,
    const unsigned int* __restrict__ abit, float* __restrict__ Lpart)
{
    const int ntile = blockIdx.x, msg = blockIdx.y;
    const int t = threadIdx.x;
    const int w = t >> 6, l = t & 63;
    const int g = l >> 4, q = l & 15;
    const int ms = msg * 4 + w;
    const int n0 = ntile * 16;
    const int mbase = ms * 256;
    bf16x8 qf[8];
    #pragma unroll
    for (int h = 0; h < 8; ++h)
        qf[h] = *(const bf16x8*)(Qb + (((size_t)h * NN + n0 + q) << 5) + g * 8);
    float lacc[8];
    #pragma unroll
    for (int h = 0; h < 8; ++h) lacc[h] = 0.f;
    for (int ch = 0; ch < 8; ++ch) {
        const int mb = mbase + ch * 32;
        const unsigned int wbits = abit[(size_t)(n0 + q) * 128 + (mb >> 5)];
        #pragma unroll
        for (int h = 0; h < 8; ++h) {
            bf16x8 ka0 = *(const bf16x8*)(Kb + (((size_t)h * NN + mb + q) << 5) + g * 8);
            bf16x8 ka1 = *(const bf16x8*)(Kb + (((size_t)h * NN + mb + 16 + q) << 5) + g * 8);
            f32x4 z = {0.f, 0.f, 0.f, 0.f};
            f32x4 s0 = __builtin_amdgcn_mfma_f32_16x16x32_bf16(ka0, qf[h], z, 0, 0, 0);
            f32x4 s1 = __builtin_amdgcn_mfma_f32_16x16x32_bf16(ka1, qf[h], z, 0, 0, 0);
            #pragma unroll
            for (int r = 0; r < 4; ++r) {
                float e0 = __expf(s0[r]);
                float e1 = __expf(s1[r]);
                lacc[h] += ((wbits >> (4 * g + r)) & 1u) ? e0 : 0.f;
                lacc[h] += ((wbits >> (16 + 4 * g + r)) & 1u) ? e1 : 0.f;
            }
        }
    }
    #pragma unroll
    for (int h = 0; h < 8; ++h) {
        float v = lacc[h];
        v += __shfl_xor(v, 16);
        v += __shfl_xor(v, 32);
        if (g == 0) Lpart[(size_t)ms * 32768 + h * NN + n0 + q] = v;
    }
}

__global__ __launch_bounds__(256, 2) void sweep2_old(
    const unsigned short* __restrict__ Qb, const unsigned short* __restrict__ Kb,
    const unsigned short* __restrict__ Vt, const unsigned int* __restrict__ abit,
    const float* __restrict__ Linv, float* __restrict__ Opart,
    float* __restrict__ amean)
{
    __shared__ __align__(16) float Ow[2 * 16 * 260];
    const int ntile = blockIdx.x, msg = blockIdx.y;
    const int t = threadIdx.x;
    const int w = t >> 6, l = t & 63;
    const int g = l >> 4, q = l & 15;
    const int ms = msg * 4 + w;
    const int n0 = ntile * 16;
    const int mbase = ms * 256;
    const int baddr = (q + (g & 1) * 32) << 2;
    const bool hi = (g >= 2);
    bf16x8 qf[8];
    float rL[8];
    #pragma unroll
    for (int h = 0; h < 8; ++h) {
        qf[h] = *(const bf16x8*)(Qb + (((size_t)h * NN + n0 + q) << 5) + g * 8);
        rL[h] = Linv[h * NN + n0 + q];
    }
    f32x4 o[8][2];
    #pragma unroll
    for (int h = 0; h < 8; ++h) {
        o[h][0] = (f32x4){0.f, 0.f, 0.f, 0.f};
        o[h][1] = (f32x4){0.f, 0.f, 0.f, 0.f};
    }
    for (int ch = 0; ch < 8; ++ch) {
        const int mb = mbase + ch * 32;
        const unsigned int wbits = abit[(size_t)(n0 + q) * 128 + (mb >> 5)];
        float am[8];
        #pragma unroll
        for (int r = 0; r < 8; ++r) am[r] = 0.f;
        #pragma unroll
        for (int h = 0; h < 8; ++h) {
            bf16x8 ka0 = *(const bf16x8*)(Kb + (((size_t)h * NN + mb + q) << 5) + g * 8);
            bf16x8 ka1 = *(const bf16x8*)(Kb + (((size_t)h * NN + mb + 16 + q) << 5) + g * 8);
            f32x4 z = {0.f, 0.f, 0.f, 0.f};
            f32x4 s0 = __builtin_amdgcn_mfma_f32_16x16x32_bf16(ka0, qf[h], z, 0, 0, 0);
            f32x4 s1 = __builtin_amdgcn_mfma_f32_16x16x32_bf16(ka1, qf[h], z, 0, 0, 0);
            float pn[8];
            #pragma unroll
            for (int r = 0; r < 4; ++r) {
                float e0 = __expf(s0[r]) * rL[h];
                float e1 = __expf(s1[r]) * rL[h];
                pn[r]     = ((wbits >> (4 * g + r)) & 1u) ? e0 : 0.f;
                pn[4 + r] = ((wbits >> (16 + 4 * g + r)) & 1u) ? e1 : 0.f;
                am[r] += pn[r];
                am[4 + r] += pn[4 + r];
            }
            unsigned int pk0 = pkbf(pn[0], pn[1]);
            unsigned int pk1 = pkbf(pn[2], pn[3]);
            unsigned int pk2 = pkbf(pn[4], pn[5]);
            unsigned int pk3 = pkbf(pn[6], pn[7]);
            int r0lo = __builtin_amdgcn_ds_bpermute(baddr,      (int)pk0);
            int r0hi = __builtin_amdgcn_ds_bpermute(baddr,      (int)pk2);
            int r1lo = __builtin_amdgcn_ds_bpermute(baddr,      (int)pk1);
            int r1hi = __builtin_amdgcn_ds_bpermute(baddr,      (int)pk3);
            int r2lo = __builtin_amdgcn_ds_bpermute(baddr + 64, (int)pk0);
            int r2hi = __builtin_amdgcn_ds_bpermute(baddr + 64, (int)pk2);
            int r3lo = __builtin_amdgcn_ds_bpermute(baddr + 64, (int)pk1);
            int r3hi = __builtin_amdgcn_ds_bpermute(baddr + 64, (int)pk3);
            union { unsigned int u[4]; bf16x8 v; } pu;
            pu.u[0] = (unsigned int)(hi ? r0hi : r0lo);
            pu.u[1] = (unsigned int)(hi ? r1hi : r1lo);
            pu.u[2] = (unsigned int)(hi ? r2hi : r2lo);
            pu.u[3] = (unsigned int)(hi ? r3hi : r3lo);
            bf16x8 va0 = *(const bf16x8*)(Vt + ((size_t)(h * 32 + q)) * NN + mb + g * 8);
            bf16x8 va1 = *(const bf16x8*)(Vt + ((size_t)(h * 32 + 16 + q)) * NN + mb + g * 8);
            o[h][0] = __builtin_amdgcn_mfma_f32_16x16x32_bf16(va0, pu.v, o[h][0], 0, 0, 0);
            o[h][1] = __builtin_amdgcn_mfma_f32_16x16x32_bf16(va1, pu.v, o[h][1], 0, 0, 0);
        }
        float4 a0, a1;
        a0.x = am[0] * 0.125f; a0.y = am[1] * 0.125f;
        a0.z = am[2] * 0.125f; a0.w = am[3] * 0.125f;
        a1.x = am[4] * 0.125f; a1.y = am[5] * 0.125f;
        a1.z = am[6] * 0.125f; a1.w = am[7] * 0.125f;
        *(float4*)(amean + (size_t)(n0 + q) * NN + mb + 4 * g) = a0;
        *(float4*)(amean + (size_t)(n0 + q) * NN + mb + 16 + 4 * g) = a1;
    }
    if (w < 2) {
        #pragma unroll
        for (int h = 0; h < 8; ++h)
            #pragma unroll
            for (int dt = 0; dt < 2; ++dt)
                *(f32x4*)&Ow[w * 4160 + q * 260 + h * 32 + dt * 16 + 4 * g] = o[h][dt];
    }
    __syncthreads();
    if (w >= 2) {
        #pragma unroll
        for (int h = 0; h < 8; ++h)
            #pragma unroll
            for (int dt = 0; dt < 2; ++dt) {
                f32x4* p = (f32x4*)&Ow[(w - 2) * 4160 + q * 260 + h * 32 + dt * 16 + 4 * g];
                *p = *p + o[h][dt];
            }
    }
    __syncthreads();
    for (int i = t; i < 4096; i += 256) {
        int n = i >> 8, c2 = i & 255;
        float v = Ow[n * 260 + c2] + Ow[4160 + n * 260 + c2];
        Opart[((size_t)msg * NN + n0 + n) * 256 + c2] = v;
    }
}

// ---------------- Linv ----------------------------------------------------
__global__ __launch_bounds__(256) void linv_kernel(
    const float* __restrict__ Lpart, float* __restrict__ Linv, int nms)
{
    int i = blockIdx.x * 256 + threadIdx.x;
    float s = 0.f;
    for (int ms = 0; ms < nms; ++ms) s += Lpart[(size_t)ms * 32768 + i];
    Linv[i] = 1.0f / s;
}

// -------- finalize: routed = (sum_ms Opart) @ Wo + bo ---------------------
__global__ __launch_bounds__(256) void final_kernel(
    const float* __restrict__ accpart, const float* __restrict__ Wo,
    const float* __restrict__ bo, float* __restrict__ routed, int nms)
{
    __shared__ float sacc[32 * 257];
    const int nb = blockIdx.x, t = threadIdx.x;
    for (int i = t; i < 8192; i += 256) {
        int r = i >> 8, c = i & 255;
        int n = nb * 32 + r;
        float s = 0.f;
        for (int ms = 0; ms < nms; ++ms)
            s += accpart[((size_t)ms * NN + n) * 256 + c];
        sacc[r * 257 + c] = s;
    }
    __syncthreads();
    const int j = t & 31, r0 = t >> 5;
    #pragma unroll
    for (int rr = 0; rr < 4; ++rr) {
        int r = r0 * 4 + rr;
        float s = bo[j];
        for (int i = 0; i < 256; ++i) s += sacc[r * 257 + i] * Wo[i * 32 + j];
        routed[(size_t)(nb * 32 + r) * 32 + j] = s;
    }
}

extern "C" void kernel_launch(void* const* d_in, const int* in_sizes, int n_in,
                              void* d_out, int out_size, void* d_ws, size_t ws_size,
                              hipStream_t stream) {
    const float* nf  = (const float*)d_in[0];
    const float* msg = (const float*)d_in[1];
    const int*   adj = (const int*)d_in[2];
    const float* Wq  = (const float*)d_in[3];
    const float* bq  = (const float*)d_in[4];
    const float* Wk  = (const float*)d_in[5];
    const float* bk  = (const float*)d_in[6];
    const float* Wv  = (const float*)d_in[7];
    const float* bv  = (const float*)d_in[8];
    const float* Wo  = (const float*)d_in[9];
    const float* bo  = (const float*)d_in[10];

    float* routed = (float*)d_out;
    float* amean  = (float*)d_out + (size_t)NN * MD;
    float* ws = (float*)d_ws;

    const bool bigws = (ws_size >= 43122688ull);   // path A needs ~43.1MB

    if (bigws) {
        // Opart: 8 x 1M floats at 0 (Qf/Kf/Vf alias its head, dead pre-sweep2)
        float* Qf = ws;
        float* Kf = ws + 1048576;
        float* Vf = ws + 2097152;
        float* Opart = ws;
        unsigned short* Qb = (unsigned short*)(ws + 8388608);
        unsigned short* Kb = (unsigned short*)(ws + 8912896);
        unsigned short* Vt = (unsigned short*)(ws + 9437184);
        unsigned int*   ab32 = (unsigned int*)(ws + 9961472);
        unsigned long long* ab64 = (unsigned long long*)(ws + 9961472);
        float* Lpart = ws + 10485760;   // 8*32768
        float* Linv  = ws + 10747904;   // 32768

        proj_kernel<<<384, 256, 0, stream>>>(nf, msg, Wq, bq, Wk, bk, Wv, bv, Qf, Kf, Vf);
        abit_kernel<<<1024, 256, 0, stream>>>(adj, ab64);
        pack_qk<<<1024, 256, 0, stream>>>(Qf, Kf, Qb, Kb);
        pack_vt<<<256, 256, 0, stream>>>(Vf, Vt, 1);
        sweep1s_kernel<<<dim3(64, 8), 256, 0, stream>>>(Qb, Kb, ab32, Lpart);
        linv_kernel<<<128, 256, 0, stream>>>(Lpart, Linv, 8);
        sweep2s_kernel<<<dim3(64, 8), 256, 0, stream>>>(Qb, Kb, Vt, ab32, Linv, Opart, amean);
        final_kernel<<<128, 256, 0, stream>>>(Opart, Wo, bo, routed, 8);
    } else {
        // round-4 proven fallback
        float* Qf = ws;
        float* Kf = ws + 1048576;
        float* Vf = ws + 2097152;
        float* Opart = ws;
        unsigned short* Qb = (unsigned short*)(ws + 4194304);
        unsigned short* Kb = (unsigned short*)(ws + 4718592);
        unsigned short* Vt = (unsigned short*)(ws + 5242880);
        unsigned int*   ab32 = (unsigned int*)(ws + 5767168);
        unsigned long long* ab64 = (unsigned long long*)(ws + 5767168);
        float* Lpart = ws + 6291456;
        float* Linv  = ws + 6815744;

        proj_kernel<<<384, 256, 0, stream>>>(nf, msg, Wq, bq, Wk, bk, Wv, bv, Qf, Kf, Vf);
        abit_kernel<<<1024, 256, 0, stream>>>(adj, ab64);
        pack_qk<<<1024, 256, 0, stream>>>(Qf, Kf, Qb, Kb);
        pack_vt<<<256, 256, 0, stream>>>(Vf, Vt, 0);
        sweep1_old<<<dim3(256, 4), 256, 0, stream>>>(Qb, Kb, ab32, Lpart);
        linv_kernel<<<128, 256, 0, stream>>>(Lpart, Linv, 16);
        sweep2_old<<<dim3(256, 4), 256, 0, stream>>>(Qb, Kb, Vt, ab32, Linv, Opart, amean);
        final_kernel<<<128, 256, 0, stream>>>(Opart, Wo, bo, routed, 4);
    }
}

// Round 7
// 197.475 us; speedup vs baseline: 1.6172x; 1.2917x over previous
//
#include <hip/hip_runtime.h>
#include <math.h>

#define NN 4096
#define HID 256
#define MD 32
#define NH 8
#define SCALE 0.17677669529663687f  // 1/sqrt(32)

typedef float f32x4 __attribute__((ext_vector_type(4)));
typedef short bf16x8 __attribute__((ext_vector_type(8)));
typedef _Float16 f16x4 __attribute__((ext_vector_type(4)));
typedef _Float16 f16x2 __attribute__((ext_vector_type(2)));

__device__ inline unsigned int bfr(float x) {             // f32 -> bf16 bits (RNE)
    unsigned int u = __float_as_uint(x);
    return (u + 0x7fffu + ((u >> 16) & 1u)) >> 16;
}
__device__ inline unsigned int pkbf(float a, float b) {
    return bfr(a) | (bfr(b) << 16);
}
__device__ inline unsigned int pkhf(float a, float b) {   // 2 x f16 (RNE)
    union { f16x2 h; unsigned int u; } z;
    z.h = (f16x2){(_Float16)a, (_Float16)b};
    return z.u;
}

// -------- Q,K projection, tiled f32, fused bf16 pack + SCALE --------------
// grid: 512 blocks (0..255 Q, 256..511 K), 16 rows each.
// inT[k][r] transposed input tile (broadcast reads); W staged in 16-k chunks.
__global__ __launch_bounds__(256, 2) void proj_qk(
    const float* __restrict__ nf,
    const float* __restrict__ Wq, const float* __restrict__ bq,
    const float* __restrict__ Wk, const float* __restrict__ bk,
    unsigned short* __restrict__ Qb, unsigned short* __restrict__ Kb)
{
    __shared__ __align__(16) float inT[256 * 20];   // [k][r], pad 20
    __shared__ __align__(16) float Wc[16 * 256];    // k-chunk x 256 cols
    const int b = blockIdx.x;
    const int isK = b >> 8;
    const int nb = b & 255;
    const float* W = isK ? Wk : Wq;
    const float* bias = isK ? bk : bq;
    unsigned short* outp = isK ? Kb : Qb;
    const int t = threadIdx.x;
    const int rg = t >> 6;             // 0..3 -> rows rg*4..+3
    const int j4 = t & 63;             // col group of 4

    for (int i = t; i < 1024; i += 256) {          // stage inT (16 rows x 256 k)
        int row = i >> 6, kq = i & 63;
        float4 v = *(const float4*)(nf + (size_t)(nb * 16 + row) * 256 + kq * 4);
        inT[(kq * 4 + 0) * 20 + row] = v.x;
        inT[(kq * 4 + 1) * 20 + row] = v.y;
        inT[(kq * 4 + 2) * 20 + row] = v.z;
        inT[(kq * 4 + 3) * 20 + row] = v.w;
    }
    float acc[4][4];
    #pragma unroll
    for (int r = 0; r < 4; ++r)
        #pragma unroll
        for (int d = 0; d < 4; ++d) acc[r][d] = 0.f;

    for (int kc = 0; kc < 16; ++kc) {
        __syncthreads();                            // inT ready / prev compute done
        for (int i = t; i < 1024; i += 256)         // stage W chunk (16 k x 256 c)
            *(float4*)&Wc[i * 4] = *(const float4*)(W + (size_t)kc * 4096 + i * 4);
        __syncthreads();
        #pragma unroll 4
        for (int k = 0; k < 16; ++k) {
            float4 iv = *(const float4*)&inT[(kc * 16 + k) * 20 + rg * 4];
            float4 wv = *(const float4*)&Wc[k * 256 + j4 * 4];
            acc[0][0] += iv.x * wv.x; acc[0][1] += iv.x * wv.y;
            acc[0][2] += iv.x * wv.z; acc[0][3] += iv.x * wv.w;
            acc[1][0] += iv.y * wv.x; acc[1][1] += iv.y * wv.y;
            acc[1][2] += iv.y * wv.z; acc[1][3] += iv.y * wv.w;
            acc[2][0] += iv.z * wv.x; acc[2][1] += iv.z * wv.y;
            acc[2][2] += iv.z * wv.z; acc[2][3] += iv.z * wv.w;
            acc[3][0] += iv.w * wv.x; acc[3][1] += iv.w * wv.y;
            acc[3][2] += iv.w * wv.z; acc[3][3] += iv.w * wv.w;
        }
    }
    const float sc = isK ? 1.0f : SCALE;
    const float4 bv = *(const float4*)(bias + j4 * 4);
    const int c0 = j4 * 4, h = c0 >> 5, d = c0 & 31;
    #pragma unroll
    for (int r = 0; r < 4; ++r) {
        int n = nb * 16 + rg * 4 + r;
        float v0 = (acc[r][0] + bv.x) * sc;
        float v1 = (acc[r][1] + bv.y) * sc;
        float v2 = (acc[r][2] + bv.z) * sc;
        float v3 = (acc[r][3] + bv.w) * sc;
        uint2 o;
        o.x = pkbf(v0, v1); o.y = pkbf(v2, v3);
        *(uint2*)(outp + ((size_t)h * NN + n) * 32 + d) = o;
    }
}

// -------- V projection (KD=32, tiny) --------------------------------------
__global__ __launch_bounds__(256) void proj_v(
    const float* __restrict__ msg, const float* __restrict__ Wv,
    const float* __restrict__ bv, float* __restrict__ Vo)
{
    __shared__ __align__(16) float in_lds[32 * 32];
    const int nb = blockIdx.x;
    const int t = threadIdx.x;
    {
        int i = t;  // 256 float4s = 1024 floats
        ((float4*)in_lds)[i] = ((const float4*)(msg + (size_t)nb * 1024))[i];
    }
    __syncthreads();
    float acc[32];
    #pragma unroll
    for (int r = 0; r < 32; ++r) acc[r] = 0.f;
    #pragma unroll 8
    for (int k = 0; k < 32; ++k) {
        float w = Wv[k * 256 + t];
        #pragma unroll
        for (int r = 0; r < 32; ++r) acc[r] += in_lds[r * 32 + k] * w;
    }
    const float bb = bv[t];
    #pragma unroll
    for (int r = 0; r < 32; ++r)
        Vo[(size_t)(nb * 32 + r) * 256 + t] = acc[r] + bb;
}

// ------------- adjacency bitmask ------------------------------------------
__global__ __launch_bounds__(256) void abit_kernel(
    const int* __restrict__ adj, unsigned long long* __restrict__ abit)
{
    const int n = blockIdx.x * 4 + (threadIdx.x >> 6);
    const int l = threadIdx.x & 63;
    for (int j = 0; j < 64; ++j) {
        int v = adj[(size_t)n * NN + j * 64 + l];
        unsigned long long m = __ballot(v != 0);
        if (l == 0) abit[(size_t)n * 64 + j] = m;
    }
}

// -------- V f32 -> transposed Vt[h][d][m] (f16 or bf16) -------------------
__global__ __launch_bounds__(256) void pack_vt(
    const float* __restrict__ Vf, unsigned short* __restrict__ Vt, int usef16)
{
    __shared__ __align__(16) float lds[128 * 33];
    const int h = blockIdx.x >> 5, mt = blockIdx.x & 31;
    const int t = threadIdx.x;
    for (int k = 0; k < 4; ++k) {
        int flat = k * 256 + t;
        int row = flat >> 3, c4 = flat & 7;
        float4 v = *(const float4*)(Vf + (size_t)(mt * 128 + row) * 256 + h * 32 + c4 * 4);
        lds[row * 33 + c4 * 4 + 0] = v.x;
        lds[row * 33 + c4 * 4 + 1] = v.y;
        lds[row * 33 + c4 * 4 + 2] = v.z;
        lds[row * 33 + c4 * 4 + 3] = v.w;
    }
    __syncthreads();
    const int d = t >> 3, mq = t & 7;
    #pragma unroll
    for (int k = 0; k < 2; ++k) {
        int m0 = mq * 16 + k * 8;
        uint4 o;
        if (usef16) {
            o.x = pkhf(lds[(m0 + 0) * 33 + d], lds[(m0 + 1) * 33 + d]);
            o.y = pkhf(lds[(m0 + 2) * 33 + d], lds[(m0 + 3) * 33 + d]);
            o.z = pkhf(lds[(m0 + 4) * 33 + d], lds[(m0 + 5) * 33 + d]);
            o.w = pkhf(lds[(m0 + 6) * 33 + d], lds[(m0 + 7) * 33 + d]);
        } else {
            o.x = pkbf(lds[(m0 + 0) * 33 + d], lds[(m0 + 1) * 33 + d]);
            o.y = pkbf(lds[(m0 + 2) * 33 + d], lds[(m0 + 3) * 33 + d]);
            o.z = pkbf(lds[(m0 + 4) * 33 + d], lds[(m0 + 5) * 33 + d]);
            o.w = pkbf(lds[(m0 + 6) * 33 + d], lds[(m0 + 7) * 33 + d]);
        }
        *(uint4*)(Vt + ((size_t)(h * 32 + d)) * NN + mt * 128 + m0) = o;
    }
}

// ======================= STAGED SWEEPS (path A) ===========================
__global__ __launch_bounds__(256, 4) void sweep1s_kernel(
    const unsigned short* __restrict__ Qb, const unsigned short* __restrict__ Kb,
    const unsigned int* __restrict__ abit, float* __restrict__ Lpart)
{
    __shared__ __align__(16) char smem[32768];
    const int nquad = blockIdx.x, msg = blockIdx.y;
    const int t = threadIdx.x;
    const int w = t >> 6, l = t & 63;
    const int g = l >> 4, q = l & 15;
    const int n0 = nquad * 64 + w * 16;
    const int m0 = msg * 512;
    const int fq = (q >> 1) & 3;

    const char* gsrc[4];
    #pragma unroll
    for (int i = 0; i < 4; ++i) {
        int s = i * 256 + t;
        int tile = s >> 7;
        int r = (s >> 2) & 31;
        int gr = (s & 3) ^ ((r >> 1) & 3);
        gsrc[i] = (const char*)Kb + (((size_t)tile * NN + m0 + r) * 64 + gr * 16);
    }
    const unsigned int* abrow = abit + (size_t)(n0 + q) * 128 + msg * 16;

    bf16x8 qf[8];
    #pragma unroll
    for (int h = 0; h < 8; ++h)
        qf[h] = *(const bf16x8*)(Qb + (((size_t)h * NN + n0 + q) << 5) + g * 8);
    float lacc[8];
    #pragma unroll
    for (int h = 0; h < 8; ++h) lacc[h] = 0.f;

    #pragma unroll
    for (int i = 0; i < 4; ++i)
        __builtin_amdgcn_global_load_lds((const unsigned int*)gsrc[i],
            (unsigned int*)(smem + i * 4096 + w * 1024), 16, 0, 0);
    unsigned int wb = abrow[0];
    unsigned int wbn = 0;
    __syncthreads();

    for (int c = 0; c < 16; ++c) {
        const char* cur = smem + (c & 1) * 16384;
        if (c < 15) {
            wbn = abrow[c + 1];
            char* nxt = smem + ((c & 1) ^ 1) * 16384;
            #pragma unroll
            for (int i = 0; i < 4; ++i)
                __builtin_amdgcn_global_load_lds(
                    (const unsigned int*)(gsrc[i] + (size_t)(c + 1) * 2048),
                    (unsigned int*)(nxt + i * 4096 + w * 1024), 16, 0, 0);
        }
        #pragma unroll
        for (int h = 0; h < 8; ++h) {
            const int ko = h * 2048 + q * 64 + ((g ^ fq) << 4);
            bf16x8 ka0 = *(const bf16x8*)(cur + ko);
            bf16x8 ka1 = *(const bf16x8*)(cur + ko + 1024);
            f32x4 z = {0.f, 0.f, 0.f, 0.f};
            f32x4 s0 = __builtin_amdgcn_mfma_f32_16x16x32_bf16(ka0, qf[h], z, 0, 0, 0);
            f32x4 s1 = __builtin_amdgcn_mfma_f32_16x16x32_bf16(ka1, qf[h], z, 0, 0, 0);
            #pragma unroll
            for (int r = 0; r < 4; ++r) {
                float e0 = __expf(s0[r]);
                float e1 = __expf(s1[r]);
                lacc[h] += ((wb >> (4 * g + r)) & 1u) ? e0 : 0.f;
                lacc[h] += ((wb >> (16 + 4 * g + r)) & 1u) ? e1 : 0.f;
            }
        }
        __syncthreads();
        wb = wbn;
    }
    #pragma unroll
    for (int h = 0; h < 8; ++h) {
        float v = lacc[h];
        v += __shfl_xor(v, 16);
        v += __shfl_xor(v, 32);
        if (g == 0) Lpart[(size_t)msg * 32768 + h * NN + n0 + q] = v;
    }
}

__global__ __launch_bounds__(256, 2) void sweep2s_kernel(
    const unsigned short* __restrict__ Qb, const unsigned short* __restrict__ Kb,
    const unsigned short* __restrict__ Vt, const unsigned int* __restrict__ abit,
    const float* __restrict__ Linv, float* __restrict__ Opart,
    float* __restrict__ amean)
{
    __shared__ __align__(16) char smem[65536];
    const int nquad = blockIdx.x, msg = blockIdx.y;
    const int t = threadIdx.x;
    const int w = t >> 6, l = t & 63;
    const int g = l >> 4, q = l & 15;
    const int n0 = nquad * 64 + w * 16;
    const int m0 = msg * 512;
    const int fq = (q >> 1) & 3;

    const char* gsrc[8];
    unsigned int gstep[8];
    #pragma unroll
    for (int i = 0; i < 8; ++i) {
        int s = i * 256 + t;
        int tile = s >> 7;
        int r = (s >> 2) & 31;
        int gr = (s & 3) ^ ((r >> 1) & 3);
        if (tile < 8) {
            gsrc[i] = (const char*)Kb + (((size_t)tile * NN + m0 + r) * 64 + gr * 16);
            gstep[i] = 2048;
        } else {
            gsrc[i] = (const char*)Vt + ((((size_t)(tile - 8) * 32 + r) * NN + m0) * 2 + gr * 16);
            gstep[i] = 64;
        }
    }
    const unsigned int* abrow = abit + (size_t)(n0 + q) * 128 + msg * 16;

    bf16x8 qf[8];
    float rL[8];
    #pragma unroll
    for (int h = 0; h < 8; ++h) {
        qf[h] = *(const bf16x8*)(Qb + (((size_t)h * NN + n0 + q) << 5) + g * 8);
        rL[h] = Linv[h * NN + n0 + q];
    }
    f32x4 o[8][2];
    #pragma unroll
    for (int h = 0; h < 8; ++h) {
        o[h][0] = (f32x4){0.f, 0.f, 0.f, 0.f};
        o[h][1] = (f32x4){0.f, 0.f, 0.f, 0.f};
    }

    #pragma unroll
    for (int i = 0; i < 8; ++i)
        __builtin_amdgcn_global_load_lds((const unsigned int*)gsrc[i],
            (unsigned int*)(smem + i * 4096 + w * 1024), 16, 0, 0);
    unsigned int wb = abrow[0];
    unsigned int wbn = 0;
    __syncthreads();

    for (int c = 0; c < 16; ++c) {
        const char* cur = smem + (c & 1) * 32768;
        if (c < 15) {
            wbn = abrow[c + 1];
            char* nxt = smem + ((c & 1) ^ 1) * 32768;
            #pragma unroll
            for (int i = 0; i < 8; ++i)
                __builtin_amdgcn_global_load_lds(
                    (const unsigned int*)(gsrc[i] + (size_t)(c + 1) * gstep[i]),
                    (unsigned int*)(nxt + i * 4096 + w * 1024), 16, 0, 0);
        }
        const int mb = m0 + c * 32;
        float am[8];
        #pragma unroll
        for (int r = 0; r < 8; ++r) am[r] = 0.f;

        #pragma unroll
        for (int h = 0; h < 8; ++h) {
            const int ko = h * 2048 + q * 64 + ((g ^ fq) << 4);
            bf16x8 ka0 = *(const bf16x8*)(cur + ko);
            bf16x8 ka1 = *(const bf16x8*)(cur + ko + 1024);
            const int vbase = (8 + h) * 2048 + q * 64 + (g & 1) * 8;
            const int vo0 = vbase + (((g >> 1) ^ fq) << 4);
            const int vo1 = vbase + (((2 + (g >> 1)) ^ fq) << 4);
            f16x4 va00 = *(const f16x4*)(cur + vo0);
            f16x4 va01 = *(const f16x4*)(cur + vo0 + 1024);
            f16x4 va10 = *(const f16x4*)(cur + vo1);
            f16x4 va11 = *(const f16x4*)(cur + vo1 + 1024);
            f32x4 z = {0.f, 0.f, 0.f, 0.f};
            f32x4 s0 = __builtin_amdgcn_mfma_f32_16x16x32_bf16(ka0, qf[h], z, 0, 0, 0);
            f32x4 s1 = __builtin_amdgcn_mfma_f32_16x16x32_bf16(ka1, qf[h], z, 0, 0, 0);
            float pn[8];
            #pragma unroll
            for (int r = 0; r < 4; ++r) {
                float e0 = __expf(s0[r]) * rL[h];
                float e1 = __expf(s1[r]) * rL[h];
                pn[r]     = ((wb >> (4 * g + r)) & 1u) ? e0 : 0.f;
                pn[4 + r] = ((wb >> (16 + 4 * g + r)) & 1u) ? e1 : 0.f;
                am[r] += pn[r];
                am[4 + r] += pn[4 + r];
            }
            union { unsigned int u[2]; f16x4 v; } pA, pB;
            pA.u[0] = pkhf(pn[0], pn[1]); pA.u[1] = pkhf(pn[2], pn[3]);
            pB.u[0] = pkhf(pn[4], pn[5]); pB.u[1] = pkhf(pn[6], pn[7]);
            o[h][0] = __builtin_amdgcn_mfma_f32_16x16x16f16(va00, pA.v, o[h][0], 0, 0, 0);
            o[h][1] = __builtin_amdgcn_mfma_f32_16x16x16f16(va01, pA.v, o[h][1], 0, 0, 0);
            o[h][0] = __builtin_amdgcn_mfma_f32_16x16x16f16(va10, pB.v, o[h][0], 0, 0, 0);
            o[h][1] = __builtin_amdgcn_mfma_f32_16x16x16f16(va11, pB.v, o[h][1], 0, 0, 0);
        }
        float4 a0, a1;
        a0.x = am[0] * 0.125f; a0.y = am[1] * 0.125f;
        a0.z = am[2] * 0.125f; a0.w = am[3] * 0.125f;
        a1.x = am[4] * 0.125f; a1.y = am[5] * 0.125f;
        a1.z = am[6] * 0.125f; a1.w = am[7] * 0.125f;
        *(float4*)(amean + (size_t)(n0 + q) * NN + mb + 4 * g) = a0;
        *(float4*)(amean + (size_t)(n0 + q) * NN + mb + 16 + 4 * g) = a1;
        __syncthreads();
        wb = wbn;
    }

    float* op = Opart + ((size_t)msg * NN + n0 + q) * 256;
    #pragma unroll
    for (int h = 0; h < 8; ++h) {
        *(f32x4*)(op + h * 32 + 4 * g) = o[h][0];
        *(f32x4*)(op + h * 32 + 16 + 4 * g) = o[h][1];
    }
}

// ======================= OLD SWEEPS (path B fallback) =====================
__global__ __launch_bounds__(256, 4) void sweep1_old(
    const unsigned short* __restrict__ Qb, const unsigned short* __restrict__ Kb,
    const unsigned int* __restrict__ abit, float* __restrict__ Lpart)
{
    const int ntile = blockIdx.x, msg = blockIdx.y;
    const int t = threadIdx.x;
    const int w = t >> 6, l = t & 63;
    const int g = l >> 4, q = l & 15;
    const int ms = msg * 4 + w;
    const int n0 = ntile * 16;
    const int mbase = ms * 256;
    bf16x8 qf[8];
    #pragma unroll
    for (int h = 0; h < 8; ++h)
        qf[h] = *(const bf16x8*)(Qb + (((size_t)h * NN + n0 + q) << 5) + g * 8);
    float lacc[8];
    #pragma unroll
    for (int h = 0; h < 8; ++h) lacc[h] = 0.f;
    for (int ch = 0; ch < 8; ++ch) {
        const int mb = mbase + ch * 32;
        const unsigned int wbits = abit[(size_t)(n0 + q) * 128 + (mb >> 5)];
        #pragma unroll
        for (int h = 0; h < 8; ++h) {
            bf16x8 ka0 = *(const bf16x8*)(Kb + (((size_t)h * NN + mb + q) << 5) + g * 8);
            bf16x8 ka1 = *(const bf16x8*)(Kb + (((size_t)h * NN + mb + 16 + q) << 5) + g * 8);
            f32x4 z = {0.f, 0.f, 0.f, 0.f};
            f32x4 s0 = __builtin_amdgcn_mfma_f32_16x16x32_bf16(ka0, qf[h], z, 0, 0, 0);
            f32x4 s1 = __builtin_amdgcn_mfma_f32_16x16x32_bf16(ka1, qf[h], z, 0, 0, 0);
            #pragma unroll
            for (int r = 0; r < 4; ++r) {
                float e0 = __expf(s0[r]);
                float e1 = __expf(s1[r]);
                lacc[h] += ((wbits >> (4 * g + r)) & 1u) ? e0 : 0.f;
                lacc[h] += ((wbits >> (16 + 4 * g + r)) & 1u) ? e1 : 0.f;
            }
        }
    }
    #pragma unroll
    for (int h = 0; h < 8; ++h) {
        float v = lacc[h];
        v += __shfl_xor(v, 16);
        v += __shfl_xor(v, 32);
        if (g == 0) Lpart[(size_t)ms * 32768 + h * NN + n0 + q] = v;
    }
}

__global__ __launch_bounds__(256, 2) void sweep2_old(
    const unsigned short* __restrict__ Qb, const unsigned short* __restrict__ Kb,
    const unsigned short* __restrict__ Vt, const unsigned int* __restrict__ abit,
    const float* __restrict__ Linv, float* __restrict__ Opart,
    float* __restrict__ amean)
{
    __shared__ __align__(16) float Ow[2 * 16 * 260];
    const int ntile = blockIdx.x, msg = blockIdx.y;
    const int t = threadIdx.x;
    const int w = t >> 6, l = t & 63;
    const int g = l >> 4, q = l & 15;
    const int ms = msg * 4 + w;
    const int n0 = ntile * 16;
    const int mbase = ms * 256;
    const int baddr = (q + (g & 1) * 32) << 2;
    const bool hi = (g >= 2);
    bf16x8 qf[8];
    float rL[8];
    #pragma unroll
    for (int h = 0; h < 8; ++h) {
        qf[h] = *(const bf16x8*)(Qb + (((size_t)h * NN + n0 + q) << 5) + g * 8);
        rL[h] = Linv[h * NN + n0 + q];
    }
    f32x4 o[8][2];
    #pragma unroll
    for (int h = 0; h < 8; ++h) {
        o[h][0] = (f32x4){0.f, 0.f, 0.f, 0.f};
        o[h][1] = (f32x4){0.f, 0.f, 0.f, 0.f};
    }
    for (int ch = 0; ch < 8; ++ch) {
        const int mb = mbase + ch * 32;
        const unsigned int wbits = abit[(size_t)(n0 + q) * 128 + (mb >> 5)];
        float am[8];
        #pragma unroll
        for (int r = 0; r < 8; ++r) am[r] = 0.f;
        #pragma unroll
        for (int h = 0; h < 8; ++h) {
            bf16x8 ka0 = *(const bf16x8*)(Kb + (((size_t)h * NN + mb + q) << 5) + g * 8);
            bf16x8 ka1 = *(const bf16x8*)(Kb + (((size_t)h * NN + mb + 16 + q) << 5) + g * 8);
            f32x4 z = {0.f, 0.f, 0.f, 0.f};
            f32x4 s0 = __builtin_amdgcn_mfma_f32_16x16x32_bf16(ka0, qf[h], z, 0, 0, 0);
            f32x4 s1 = __builtin_amdgcn_mfma_f32_16x16x32_bf16(ka1, qf[h], z, 0, 0, 0);
            float pn[8];
            #pragma unroll
            for (int r = 0; r < 4; ++r) {
                float e0 = __expf(s0[r]) * rL[h];
                float e1 = __expf(s1[r]) * rL[h];
                pn[r]     = ((wbits >> (4 * g + r)) & 1u) ? e0 : 0.f;
                pn[4 + r] = ((wbits >> (16 + 4 * g + r)) & 1u) ? e1 : 0.f;
                am[r] += pn[r];
                am[4 + r] += pn[4 + r];
            }
            unsigned int pk0 = pkbf(pn[0], pn[1]);
            unsigned int pk1 = pkbf(pn[2], pn[3]);
            unsigned int pk2 = pkbf(pn[4], pn[5]);
            unsigned int pk3 = pkbf(pn[6], pn[7]);
            int r0lo = __builtin_amdgcn_ds_bpermute(baddr,      (int)pk0);
            int r0hi = __builtin_amdgcn_ds_bpermute(baddr,      (int)pk2);
            int r1lo = __builtin_amdgcn_ds_bpermute(baddr,      (int)pk1);
            int r1hi = __builtin_amdgcn_ds_bpermute(baddr,      (int)pk3);
            int r2lo = __builtin_amdgcn_ds_bpermute(baddr + 64, (int)pk0);
            int r2hi = __builtin_amdgcn_ds_bpermute(baddr + 64, (int)pk2);
            int r3lo = __builtin_amdgcn_ds_bpermute(baddr + 64, (int)pk1);
            int r3hi = __builtin_amdgcn_ds_bpermute(baddr + 64, (int)pk3);
            union { unsigned int u[4]; bf16x8 v; } pu;
            pu.u[0] = (unsigned int)(hi ? r0hi : r0lo);
            pu.u[1] = (unsigned int)(hi ? r1hi : r1lo);
            pu.u[2] = (unsigned int)(hi ? r2hi : r2lo);
            pu.u[3] = (unsigned int)(hi ? r3hi : r3lo);
            bf16x8 va0 = *(const bf16x8*)(Vt + ((size_t)(h * 32 + q)) * NN + mb + g * 8);
            bf16x8 va1 = *(const bf16x8*)(Vt + ((size_t)(h * 32 + 16 + q)) * NN + mb + g * 8);
            o[h][0] = __builtin_amdgcn_mfma_f32_16x16x32_bf16(va0, pu.v, o[h][0], 0, 0, 0);
            o[h][1] = __builtin_amdgcn_mfma_f32_16x16x32_bf16(va1, pu.v, o[h][1], 0, 0, 0);
        }
        float4 a0, a1;
        a0.x = am[0] * 0.125f; a0.y = am[1] * 0.125f;
        a0.z = am[2] * 0.125f; a0.w = am[3] * 0.125f;
        a1.x = am[4] * 0.125f; a1.y = am[5] * 0.125f;
        a1.z = am[6] * 0.125f; a1.w = am[7] * 0.125f;
        *(float4*)(amean + (size_t)(n0 + q) * NN + mb + 4 * g) = a0;
        *(float4*)(amean + (size_t)(n0 + q) * NN + mb + 16 + 4 * g) = a1;
    }
    if (w < 2) {
        #pragma unroll
        for (int h = 0; h < 8; ++h)
            #pragma unroll
            for (int dt = 0; dt < 2; ++dt)
                *(f32x4*)&Ow[w * 4160 + q * 260 + h * 32 + dt * 16 + 4 * g] = o[h][dt];
    }
    __syncthreads();
    if (w >= 2) {
        #pragma unroll
        for (int h = 0; h < 8; ++h)
            #pragma unroll
            for (int dt = 0; dt < 2; ++dt) {
                f32x4* p = (f32x4*)&Ow[(w - 2) * 4160 + q * 260 + h * 32 + dt * 16 + 4 * g];
                *p = *p + o[h][dt];
            }
    }
    __syncthreads();
    for (int i = t; i < 4096; i += 256) {
        int n = i >> 8, c2 = i & 255;
        float v = Ow[n * 260 + c2] + Ow[4160 + n * 260 + c2];
        Opart[((size_t)msg * NN + n0 + n) * 256 + c2] = v;
    }
}

// ---------------- Linv ----------------------------------------------------
__global__ __launch_bounds__(256) void linv_kernel(
    const float* __restrict__ Lpart, float* __restrict__ Linv, int nms)
{
    int i = blockIdx.x * 256 + threadIdx.x;
    float s = 0.f;
    for (int ms = 0; ms < nms; ++ms) s += Lpart[(size_t)ms * 32768 + i];
    Linv[i] = 1.0f / s;
}

// -------- finalize: routed = (sum_ms Opart) @ Wo + bo ---------------------
// 256 blocks x 16 rows; WoT + Osum in LDS; 2 rows/thread, dual accumulators.
__global__ __launch_bounds__(256) void final_kernel(
    const float* __restrict__ Opart, const float* __restrict__ Wo,
    const float* __restrict__ bo, float* __restrict__ routed, int nms)
{
    __shared__ __align__(16) float Osum[16 * 260];
    __shared__ __align__(16) float WoT[32 * 260];
    const int nb = blockIdx.x, t = threadIdx.x;
    for (int i4 = t; i4 < 2048; i4 += 256) {        // stage WoT[c][k]
        int k = i4 >> 3, j4b = i4 & 7;
        float4 v = *(const float4*)(Wo + k * 32 + j4b * 4);
        WoT[(j4b * 4 + 0) * 260 + k] = v.x;
        WoT[(j4b * 4 + 1) * 260 + k] = v.y;
        WoT[(j4b * 4 + 2) * 260 + k] = v.z;
        WoT[(j4b * 4 + 3) * 260 + k] = v.w;
    }
    for (int i = t; i < 4096; i += 256) {           // stage Osum (16 rows)
        int r = i >> 8, c = i & 255;
        const float* ap = Opart + ((size_t)(nb * 16 + r)) * 256 + c;
        float s = 0.f;
        for (int ms = 0; ms < nms; ++ms) s += ap[(size_t)ms * 1048576];
        Osum[r * 260 + c] = s;
    }
    __syncthreads();
    const int rh = t >> 5, j = t & 31;
    const float bj = bo[j];
    #pragma unroll
    for (int rr = 0; rr < 2; ++rr) {
        int r = rh * 2 + rr;
        float a0 = 0.f, a1 = 0.f;
        #pragma unroll
        for (int i4 = 0; i4 < 64; i4 += 2) {
            float4 ov = *(const float4*)&Osum[r * 260 + i4 * 4];
            float4 wv = *(const float4*)&WoT[j * 260 + i4 * 4];
            a0 += ov.x * wv.x + ov.y * wv.y + ov.z * wv.z + ov.w * wv.w;
            float4 ov2 = *(const float4*)&Osum[r * 260 + i4 * 4 + 4];
            float4 wv2 = *(const float4*)&WoT[j * 260 + i4 * 4 + 4];
            a1 += ov2.x * wv2.x + ov2.y * wv2.y + ov2.z * wv2.z + ov2.w * wv2.w;
        }
        routed[(size_t)(nb * 16 + r) * 32 + j] = a0 + a1 + bj;
    }
}

extern "C" void kernel_launch(void* const* d_in, const int* in_sizes, int n_in,
                              void* d_out, int out_size, void* d_ws, size_t ws_size,
                              hipStream_t stream) {
    const float* nf  = (const float*)d_in[0];
    const float* msg = (const float*)d_in[1];
    const int*   adj = (const int*)d_in[2];
    const float* Wq  = (const float*)d_in[3];
    const float* bq  = (const float*)d_in[4];
    const float* Wk  = (const float*)d_in[5];
    const float* bk  = (const float*)d_in[6];
    const float* Wv  = (const float*)d_in[7];
    const float* bv  = (const float*)d_in[8];
    const float* Wo  = (const float*)d_in[9];
    const float* bo  = (const float*)d_in[10];

    float* routed = (float*)d_out;
    float* amean  = (float*)d_out + (size_t)NN * MD;
    float* ws = (float*)d_ws;

    const bool bigws = (ws_size >= 43122688ull);

    if (bigws) {
        float* Vf = ws;                 // aliases Opart head; dead before sweep2s
        float* Opart = ws;              // 8 x 1M floats
        unsigned short* Qb = (unsigned short*)(ws + 8388608);
        unsigned short* Kb = (unsigned short*)(ws + 8912896);
        unsigned short* Vt = (unsigned short*)(ws + 9437184);
        unsigned int*   ab32 = (unsigned int*)(ws + 9961472);
        unsigned long long* ab64 = (unsigned long long*)(ws + 9961472);
        float* Lpart = ws + 10485760;
        float* Linv  = ws + 10747904;

        proj_qk<<<512, 256, 0, stream>>>(nf, Wq, bq, Wk, bk, Qb, Kb);
        proj_v<<<128, 256, 0, stream>>>(msg, Wv, bv, Vf);
        abit_kernel<<<1024, 256, 0, stream>>>(adj, ab64);
        pack_vt<<<256, 256, 0, stream>>>(Vf, Vt, 1);
        sweep1s_kernel<<<dim3(64, 8), 256, 0, stream>>>(Qb, Kb, ab32, Lpart);
        linv_kernel<<<128, 256, 0, stream>>>(Lpart, Linv, 8);
        sweep2s_kernel<<<dim3(64, 8), 256, 0, stream>>>(Qb, Kb, Vt, ab32, Linv, Opart, amean);
        final_kernel<<<256, 256, 0, stream>>>(Opart, Wo, bo, routed, 8);
    } else {
        float* Vf = ws;
        float* Opart = ws;              // 4 x 1M floats
        unsigned short* Qb = (unsigned short*)(ws + 4194304);
        unsigned short* Kb = (unsigned short*)(ws + 4718592);
        unsigned short* Vt = (unsigned short*)(ws + 5242880);
        unsigned int*   ab32 = (unsigned int*)(ws + 5767168);
        unsigned long long* ab64 = (unsigned long long*)(ws + 5767168);
        float* Lpart = ws + 6291456;
        float* Linv  = ws + 6815744;

        proj_qk<<<512, 256, 0, stream>>>(nf, Wq, bq, Wk, bk, Qb, Kb);
        proj_v<<<128, 256, 0, stream>>>(msg, Wv, bv, Vf);
        abit_kernel<<<1024, 256, 0, stream>>>(adj, ab64);
        pack_vt<<<256, 256, 0, stream>>>(Vf, Vt, 0);
        sweep1_old<<<dim3(256, 4), 256, 0, stream>>>(Qb, Kb, ab32, Lpart);
        linv_kernel<<<128, 256, 0, stream>>>(Lpart, Linv, 16);
        sweep2_old<<<dim3(256, 4), 256, 0, stream>>>(Qb, Kb, Vt, ab32, Linv, Opart, amean);
        final_kernel<<<128, 256, 0, stream>>>(Opart, Wo, bo, routed, 4);
    }
}